// Round 20
// baseline (433.352 us; speedup 1.0000x reference)
//
#include <hip/hip_runtime.h>

#define NN 16384      // nodes
#define NE 262144     // edges
#define NSPEC 10
#define KC 64
#define MLPH 16
#define SEG 128       // edge segments
#define EPSG 2048     // edges per segment = NE/SEG
#define SC_NPB 16     // k_sc nodes per block (4 waves x 4)

typedef float v2f __attribute__((ext_vector_type(2)));

__device__ __forceinline__ float wave_reduce(float v) {
#pragma unroll
    for (int off = 32; off > 0; off >>= 1) v += __shfl_down(v, off, 64);
    return v;
}

__device__ __forceinline__ float f4c(const float4& v, int j) {
    const float* p = &v.x;   // j compile-time after unroll
    return p[j];
}

// 128 blocks x 1024 threads. Per-block PRIVATE full histogram in LDS (64 KB):
// eslot[e] = rank of edge within (segment, receiver) -- LDS fetch-add.
__global__ void __launch_bounds__(1024) k_pre(
    const float* __restrict__ W_embed,
    const int* __restrict__ species,
    const int* __restrict__ receivers,
    int* __restrict__ eslot,
    unsigned short* __restrict__ cnt16,    // [SEG][NN]
    float4* __restrict__ h04) {
    __shared__ int cntL[NN];
    int t = threadIdx.x;
#pragma unroll
    for (int i = 0; i < 16; ++i) cntL[t + 1024 * i] = 0;
    __syncthreads();
    int ebase = blockIdx.x * EPSG;
#pragma unroll
    for (int j = 0; j < EPSG / 1024; ++j) {
        int e = ebase + j * 1024 + t;
        int r = receivers[e];
        eslot[e] = atomicAdd(&cntL[r], 1);   // LDS atomic (ds_add_rtn)
    }
    int gt = blockIdx.x * 1024 + t;
#pragma unroll
    for (int q = 0; q < 2; ++q) {
        int idx = gt * 2 + q;
        int n = idx >> 4, w = idx & 15;
        h04[idx] = reinterpret_cast<const float4*>(W_embed + species[n] * KC)[w];
    }
    __syncthreads();
    unsigned short* o = cnt16 + (size_t)blockIdx.x * NN;
#pragma unroll
    for (int i = 0; i < 16; ++i)
        o[t + 1024 * i] = (unsigned short)cntL[t + 1024 * i];
}

// per-receiver column scan across segments (coalesced: thread = receiver)
__global__ void __launch_bounds__(128) k_colscan(
    const unsigned short* __restrict__ cnt16,
    int* __restrict__ seg_base,            // [SEG][NN]
    int* __restrict__ count) {
    int r = blockIdx.x * 128 + threadIdx.x;
    int run = 0;
#pragma unroll 8
    for (int g = 0; g < SEG; ++g) {
        int c = cnt16[(size_t)g * NN + r];
        seg_base[(size_t)g * NN + r] = run;
        run += c;
    }
    count[r] = run;
}

// single block: row_start scan + deterministic ballot-based species ranking
__global__ void __launch_bounds__(1024) k_scan(
    const int* __restrict__ count, int* __restrict__ row_start,
    const int* __restrict__ species, int* __restrict__ nslot,
    int* __restrict__ sp_start) {
    __shared__ int lds[1024];
    __shared__ int itercnt[256 * NSPEC];
    __shared__ int spt[NSPEC];
    int t = threadIdx.x;
    int lane = t & 63;
    int w = t >> 6;
#pragma unroll
    for (int j = 0; j < 16; ++j) {
        int n = w * 1024 + j * 64 + lane;
        int sp = species[n];
#pragma unroll
        for (int s = 0; s < NSPEC; ++s) {
            unsigned long long mask = __ballot(sp == s);
            if (lane == 0) itercnt[(w * 16 + j) * NSPEC + s] = (int)__popcll(mask);
        }
    }
    int base = t * 16;
    int local[16];
    int ssum = 0;
#pragma unroll
    for (int b = 0; b < 16; ++b) { local[b] = count[base + b]; ssum += local[b]; }
    lds[t] = ssum;
    __syncthreads();
    for (int off = 1; off < 1024; off <<= 1) {
        int v = (t >= off) ? lds[t - off] : 0;
        __syncthreads();
        lds[t] += v;
        __syncthreads();
    }
    int run = lds[t] - ssum;
#pragma unroll
    for (int b = 0; b < 16; ++b) { row_start[base + b] = run; run += local[b]; }
    if (t == 1023) row_start[NN] = run;
    __syncthreads();
    // per-species exclusive scan over 256 iter-entries: one wave per species
    if (w < NSPEC) {
        int s = w;
        int v0 = itercnt[(lane * 4 + 0) * NSPEC + s];
        int v1 = itercnt[(lane * 4 + 1) * NSPEC + s];
        int v2 = itercnt[(lane * 4 + 2) * NSPEC + s];
        int v3 = itercnt[(lane * 4 + 3) * NSPEC + s];
        int ls = v0 + v1 + v2 + v3;
        int inc = ls;
#pragma unroll
        for (int off = 1; off < 64; off <<= 1) {
            int v = __shfl_up(inc, off, 64);
            if (lane >= off) inc += v;
        }
        int exc = inc - ls;
        itercnt[(lane * 4 + 0) * NSPEC + s] = exc;
        itercnt[(lane * 4 + 1) * NSPEC + s] = exc + v0;
        itercnt[(lane * 4 + 2) * NSPEC + s] = exc + v0 + v1;
        itercnt[(lane * 4 + 3) * NSPEC + s] = exc + v0 + v1 + v2;
        if (lane == 63) spt[s] = inc;
    }
    __syncthreads();
    if (t == 0) {
        int r2 = 0;
        for (int s = 0; s < NSPEC; ++s) { sp_start[s] = r2; r2 += spt[s]; }
        sp_start[NSPEC] = r2;
    }
    __syncthreads();
#pragma unroll
    for (int j = 0; j < 16; ++j) {
        int n = w * 1024 + j * 64 + lane;
        int sp = species[n];
        int rank = 0;
#pragma unroll
        for (int s = 0; s < NSPEC; ++s) {
            unsigned long long mask = __ballot(sp == s);
            if (sp == s)
                rank = (int)__popcll(mask & ((1ull << lane) - 1ull));
        }
        nslot[n] = itercnt[(w * 16 + j) * NSPEC + sp] + rank;
    }
}

// geometry: 64B record [Y1..Y8, rad0..7] + separate sender array.
// sin via hardware v_sin_f32 (revolutions).  Also scatters ord.
__global__ void k_geom(const float* __restrict__ pos,
                       const float* __restrict__ shifts,
                       const int* __restrict__ senders,
                       const int* __restrict__ receivers,
                       const int* __restrict__ row_start,
                       const int* __restrict__ seg_base,
                       const int* __restrict__ eslot,
                       const int* __restrict__ species,
                       const int* __restrict__ sp_start,
                       const int* __restrict__ nslot,
                       int* __restrict__ ord,
                       float* __restrict__ edgerec,
                       int* __restrict__ ssend) {
    int e = blockIdx.x * 256 + threadIdx.x;
    if (e < NN) {
        int sp = species[e];
        ord[sp_start[sp] + nslot[e]] = e;
    }
    int s = senders[e], r = receivers[e];
    float dx = pos[r * 3 + 0] - pos[s * 3 + 0] + shifts[e * 3 + 0];
    float dy = pos[r * 3 + 1] - pos[s * 3 + 1] + shifts[e * 3 + 1];
    float dz = pos[r * 3 + 2] - pos[s * 3 + 2] + shifts[e * 3 + 2];
    float rn = sqrtf(dx * dx + dy * dy + dz * dz);
    float den = (rn > 1e-9f) ? rn : 1.0f;
    float x = dx / den, y = dy / den, z = dz / den;
    const float s3  = 1.7320508075688772f;
    const float s15 = 3.8729833462074170f;
    const float s5h = 1.1180339887498949f;
    const float s15h = 1.9364916731037085f;
    float rec[16];
    rec[0] = s3 * x;
    rec[1] = s3 * y;
    rec[2] = s3 * z;
    rec[3] = s15 * x * y;
    rec[4] = s15 * y * z;
    rec[5] = s5h * (3.0f * z * z - 1.0f);
    rec[6] = s15 * x * z;
    rec[7] = s15h * (x * x - y * y);
    float u = rn * 0.2f;
    float env = 0.0f;
    if (u < 1.0f) {
        float u2 = u * u;
        float u5 = u2 * u2 * u;
        env = 1.0f - 21.0f * u5 + 35.0f * u5 * u - 15.0f * u5 * u2;
    }
    float pre = 0.63245553203367587f * env / den;
    float half_u = 0.5f * u;
#pragma unroll
    for (int nb = 1; nb <= 8; ++nb) {
        float tr = (float)nb * half_u;       // revolutions
        tr -= floorf(tr);
        rec[7 + nb] = pre * __builtin_amdgcn_sinf(tr);
    }
    int p = row_start[r] + seg_base[(size_t)(e >> 11) * NN + r] + eslot[e];
    float4* o = (float4*)(edgerec + (size_t)p * 16);
#pragma unroll
    for (int i = 0; i < 4; ++i)
        o[i] = make_float4(rec[4 * i], rec[4 * i + 1], rec[4 * i + 2], rec[4 * i + 3]);
    ssend[p] = s;
}

// packed-fp32 per-edge accumulate; rec = [Y1..Y8, rad0..7], Y0==1 implicit.
// rc points into LDS (wave-private staging) -- uniform broadcast reads.
__device__ __forceinline__ void agg_edge_pk(
    const float* rc, float hv,
    const float (&Wr0)[8], const v2f (&Wr12)[8],
    float& acc0, v2f (&accp)[4]) {
    float R0 = 0.f;
    v2f R12 = (v2f){0.f, 0.f};
#pragma unroll
    for (int b = 0; b < 8; ++b) {
        float rb = rc[8 + b];
        R0 = fmaf(rb, Wr0[b], R0);
        R12 = __builtin_elementwise_fma((v2f){rb, rb}, Wr12[b], R12);
    }
    acc0 = fmaf(hv, R0, acc0);
    float t1 = hv * R12.x, t2 = hv * R12.y;
    accp[0] = __builtin_elementwise_fma((v2f){t1, t1}, (v2f){rc[0], rc[1]}, accp[0]);
    accp[1] = __builtin_elementwise_fma((v2f){t1, t2}, (v2f){rc[2], rc[3]}, accp[1]);
    accp[2] = __builtin_elementwise_fma((v2f){t2, t2}, (v2f){rc[4], rc[5]}, accp[2]);
    accp[3] = __builtin_elementwise_fma((v2f){t2, t2}, (v2f){rc[6], rc[7]}, accp[3]);
}

// fused aggregate + mix + prod.  Edge records now loaded via the VECTOR path
// (coalesced 256B per 4 edges -> wave-private LDS strip -> uniform b128
// broadcast reads), removing the 17 MB scalar-cache stream that serialized
// the K$.  Senders bulk-loaded + shfl.  LDS 34 KB -> 4 blocks/CU (32 waves).
__global__ void __launch_bounds__(512, 8) k_aggmix(
    const float* __restrict__ h,
    const float* __restrict__ edgerec,
    const int* __restrict__ ssend,
    const int* __restrict__ row_start,
    const float* __restrict__ Wr_i,    // [3][8][64]
    const float* __restrict__ Wm_i,    // [3][64][64]
    const float* __restrict__ Wp_i,    // [3][3][64]
    float* __restrict__ Bm0) {
    __shared__ float Wlds[4096];       // 16 KB: W_mix l=2
    __shared__ float xtile[8][9 * 64]; // 18 KB
    {
        float4* Wl4 = (float4*)Wlds;
        const float4* W4 = (const float4*)(Wm_i + 2 * 4096);   // l=2 start
#pragma unroll
        for (int i = 0; i < 2; ++i)
            Wl4[threadIdx.x + 512 * i] = W4[threadIdx.x + 512 * i];
    }
    __syncthreads();
    int lane = threadIdx.x & 63;
    int wid = __builtin_amdgcn_readfirstlane(threadIdx.x >> 6);
    float* xt = xtile[wid];
    float Wr0[8];
    v2f  Wr12[8];
#pragma unroll
    for (int b = 0; b < 8; ++b) {
        Wr0[b]    = Wr_i[b * 64 + lane] * (1.0f / 16.0f);
        Wr12[b].x = Wr_i[(8 + b) * 64 + lane] * (1.0f / 16.0f);
        Wr12[b].y = Wr_i[(16 + b) * 64 + lane] * (1.0f / 16.0f);
    }
    float w10 = Wp_i[0 * 64 + lane];
    float w20 = Wp_i[3 * 64 + lane];
    float w30 = Wp_i[6 * 64 + lane];
    const float* W0g = Wm_i;           // l=0 from global (L1)
    const float* W1g = Wm_i + 4096;    // l=1 from global (L1)

    int nA = (blockIdx.x * 8 + wid) * 2;
    int nB = nA + 1;
    int eA0 = row_start[nA], eA1 = row_start[nA + 1], eB1 = row_start[nB + 1];
    int eB0 = eA1;
    int cA = eA1 - eA0, cB = eB1 - eB0;

    // bulk senders (coalesced vector load + shfl broadcast)
    int sAllA = ssend[cA ? min(eA0 + lane, eA1 - 1) : 0];
    int sAllB = ssend[cB ? min(eB0 + lane, eB1 - 1) : 0];

    float accA0 = 0.f, accB0 = 0.f;
    v2f accAp[4], accBp[4];
#pragma unroll
    for (int q = 0; q < 4; ++q) { accAp[q] = (v2f){0.f, 0.f}; accBp[q] = (v2f){0.f, 0.f}; }

    int ngA = (cA + 3) >> 2, ngB = (cB + 3) >> 2;
    int ng = max(ngA, ngB);
    for (int gg = 0; gg < ng; ++gg) {
        int baseA = eA0 + gg * 4, baseB = eB0 + gg * 4;
        int remA = eA1 - baseA; remA = (remA < 0) ? 0 : ((remA > 4) ? 4 : remA);
        int remB = eB1 - baseB; remB = (remB < 0) ? 0 : ((remB > 4) ? 4 : remB);
        // vector-path record loads: 4 records / wave / node, coalesced 256B
        if (remA > 0) {
            int src = min(baseA * 16 + lane, eA1 * 16 - 1);
            xt[lane] = edgerec[src];
        }
        if (remB > 0) {
            int src = min(baseB * 16 + lane, eB1 * 16 - 1);
            xt[64 + lane] = edgerec[src];
        }
        int rm = min(remA, remB);
#pragma unroll 4
        for (int i = 0; i < rm; ++i) {
            int idx = gg * 4 + i;
            int sa = (idx < 64) ? __shfl(sAllA, idx, 64) : ssend[baseA + i];
            int sb = (idx < 64) ? __shfl(sAllB, idx, 64) : ssend[baseB + i];
            float ha = h[(size_t)sa * 64 + lane];
            float hb = h[(size_t)sb * 64 + lane];
            agg_edge_pk(xt + 16 * i, ha, Wr0, Wr12, accA0, accAp);
            agg_edge_pk(xt + 64 + 16 * i, hb, Wr0, Wr12, accB0, accBp);
        }
#pragma unroll 4
        for (int i = rm; i < remA; ++i) {
            int idx = gg * 4 + i;
            int sa = (idx < 64) ? __shfl(sAllA, idx, 64) : ssend[baseA + i];
            float ha = h[(size_t)sa * 64 + lane];
            agg_edge_pk(xt + 16 * i, ha, Wr0, Wr12, accA0, accAp);
        }
#pragma unroll 4
        for (int i = rm; i < remB; ++i) {
            int idx = gg * 4 + i;
            int sb = (idx < 64) ? __shfl(sAllB, idx, 64) : ssend[baseB + i];
            float hb = h[(size_t)sb * 64 + lane];
            agg_edge_pk(xt + 64 + 16 * i, hb, Wr0, Wr12, accB0, accBp);
        }
    }

#pragma unroll
    for (int nn = 0; nn < 2; ++nn) {
        float a0 = nn ? accB0 : accA0;
        v2f* ap = nn ? accBp : accAp;
        int n = nn ? nB : nA;
        xt[0 * 64 + lane] = a0;
        xt[1 * 64 + lane] = ap[0].x;  xt[2 * 64 + lane] = ap[0].y;
        xt[3 * 64 + lane] = ap[1].x;  xt[4 * 64 + lane] = ap[1].y;
        xt[5 * 64 + lane] = ap[2].x;  xt[6 * 64 + lane] = ap[2].y;
        xt[7 * 64 + lane] = ap[3].x;  xt[8 * 64 + lane] = ap[3].y;
        v2f mixp[9];
#pragma unroll
        for (int m = 0; m < 9; ++m) mixp[m] = (v2f){0.f, 0.f};
#pragma unroll 2
        for (int c4 = 0; c4 < 16; ++c4) {
            float4 xb[9];
#pragma unroll
            for (int m = 0; m < 9; ++m)
                xb[m] = *(const float4*)&xt[m * 64 + c4 * 4];   // uniform b128
#pragma unroll
            for (int j2 = 0; j2 < 2; ++j2) {
                int k0 = c4 * 4 + j2 * 2;
                v2f wv0 = (v2f){W0g[k0 * 64 + lane], W0g[(k0 + 1) * 64 + lane]};
                v2f wv1 = (v2f){W1g[k0 * 64 + lane], W1g[(k0 + 1) * 64 + lane]};
                v2f wv2 = (v2f){Wlds[k0 * 64 + lane], Wlds[(k0 + 1) * 64 + lane]};
#pragma unroll
                for (int m = 0; m < 9; ++m) {
                    v2f xp = (v2f){f4c(xb[m], j2 * 2), f4c(xb[m], j2 * 2 + 1)};
                    v2f wv = (m == 0) ? wv0 : ((m < 4) ? wv1 : wv2);
                    mixp[m] = __builtin_elementwise_fma(xp, wv, mixp[m]);
                }
            }
        }
        float mix[9];
#pragma unroll
        for (int m = 0; m < 9; ++m) mix[m] = mixp[m].x + mixp[m].y;
        float A0 = mix[0];
        float inv = 0.f;
#pragma unroll
        for (int m = 0; m < 9; ++m) inv += mix[m] * mix[m];
        Bm0[(size_t)n * 64 + lane] = mix[0] * (w10 + w20 * A0 + w30 * inv);
    }
}

// l=0 self-connection + energy epilogue.  Balanced grid: block b owns sorted
// slots [b*16, b*16+16) of ord -- every block works.  W of first node's
// species staged in LDS; rare species-boundary nodes recomputed via global W.
template <int ITER>
__global__ void __launch_bounds__(256) k_sc(
    const float* __restrict__ h_in,
    const float* __restrict__ Bm0,
    float* __restrict__ h_out,
    const int* __restrict__ ord,
    const int* __restrict__ species,
    const float* __restrict__ Wsc_i,     // + sp*3*4096 selects [sp][l=0]
    const float* __restrict__ W_ro0,
    const float* __restrict__ W_m1,
    const float* __restrict__ b_m1,
    const float* __restrict__ W_m2,
    float* __restrict__ out) {
    __shared__ float Wlds[4096];
    __shared__ float xtile[4][4 * 64];
    int idx0 = blockIdx.x * SC_NPB;
    int s0 = species[ord[idx0]];          // uniform -> scalar loads
    {
        const float4* W4 = (const float4*)(Wsc_i + (size_t)s0 * 3 * 4096);
        float4* Wl4 = (float4*)Wlds;
#pragma unroll
        for (int i = 0; i < 4; ++i)
            Wl4[threadIdx.x + 256 * i] = W4[threadIdx.x + 256 * i];
    }
    __syncthreads();
    int lane = threadIdx.x & 63;
    int wid = threadIdx.x >> 6;
    float* xt = xtile[wid];
    int q0 = idx0 + wid * 4;
    int nd[4];
#pragma unroll
    for (int t = 0; t < 4; ++t) nd[t] = ord[q0 + t];
    float xv[4];
#pragma unroll
    for (int t = 0; t < 4; ++t) xv[t] = h_in[(size_t)nd[t] * 64 + lane];
#pragma unroll
    for (int t = 0; t < 4; ++t) xt[t * 64 + lane] = xv[t];
    float acc[4] = {0.f, 0.f, 0.f, 0.f};
#pragma unroll 4
    for (int c4 = 0; c4 < 16; ++c4) {
        float wv[4];
#pragma unroll
        for (int j = 0; j < 4; ++j) wv[j] = Wlds[(c4 * 4 + j) * 64 + lane];
#pragma unroll
        for (int t = 0; t < 4; ++t) {
            float4 xb = *(const float4*)&xt[t * 64 + c4 * 4];
#pragma unroll
            for (int j = 0; j < 4; ++j) acc[t] += f4c(xb, j) * wv[j];
        }
    }
    // rare species-boundary fixup (wave-uniform condition)
#pragma unroll
    for (int t = 0; t < 4; ++t) {
        int spt = species[nd[t]];
        if (spt != s0) {
            const float* Wg = Wsc_i + (size_t)spt * 3 * 4096;
            float a = 0.f;
            for (int k = 0; k < 64; ++k)
                a += xt[t * 64 + k] * Wg[k * 64 + lane];
            acc[t] = a;
        }
    }
    float wro = W_ro0[lane];
#pragma unroll
    for (int t = 0; t < 4; ++t) {
        int node = nd[t];
        float outv = acc[t] + Bm0[(size_t)node * 64 + lane];
        if (ITER == 0) {
            h_out[(size_t)node * 64 + lane] = outv;
            float e = wave_reduce(outv * wro);
            if (lane == 0) out[2 * node + 0] = e;
        } else {
            int hh = lane & 15;
            float tacc = b_m1[hh];
#pragma unroll
            for (int k = 0; k < 64; ++k)
                tacc += __shfl(outv, k, 64) * W_m1[k * MLPH + hh];
            float sig = 1.0f / (1.0f + expf(-tacc));
            float contrib = (lane < MLPH) ? tacc * sig * W_m2[lane] : 0.f;
            float e = wave_reduce(contrib);
            if (lane == 0) out[2 * node + 1] = e;
        }
    }
}

extern "C" void kernel_launch(void* const* d_in, const int* in_sizes, int n_in,
                              void* d_out, int out_size, void* d_ws, size_t ws_size,
                              hipStream_t stream) {
    const float* positions = (const float*)d_in[0];
    const float* shifts    = (const float*)d_in[1];
    const int*   species   = (const int*)d_in[2];
    const int*   senders   = (const int*)d_in[3];
    const int*   receivers = (const int*)d_in[4];
    const float* W_embed   = (const float*)d_in[5];
    const float* W_rad     = (const float*)d_in[6];
    const float* W_mix     = (const float*)d_in[7];
    const float* W_prod    = (const float*)d_in[8];
    const float* W_sc      = (const float*)d_in[9];
    const float* W_ro0     = (const float*)d_in[10];
    const float* W_m1      = (const float*)d_in[11];
    const float* b_m1      = (const float*)d_in[12];
    const float* W_m2      = (const float*)d_in[13];
    float* out = (float*)d_out;

    char* p = (char*)d_ws;
    float* edgerec = (float*)p; p += (size_t)NE * 16 * 4;    // 16.78 MB
    int* seg_base  = (int*)p;   p += (size_t)SEG * NN * 4;   //  8.39 MB
    float* Bm0     = (float*)p; p += (size_t)NN * KC * 4;    //  4.19 MB
    float* h0      = (float*)p; p += (size_t)NN * KC * 4;    //  4.19 MB
    float* h1      = (float*)p; p += (size_t)NN * KC * 4;    //  4.19 MB
    unsigned short* cnt16 = (unsigned short*)p; p += (size_t)SEG * NN * 2; // 4.19 MB
    int* eslot     = (int*)p; p += (size_t)NE * 4;           //  1.05 MB
    int* ssend     = (int*)p; p += (size_t)NE * 4;           //  1.05 MB
    int* nslot     = (int*)p; p += (size_t)NN * 4;
    int* ord       = (int*)p; p += (size_t)NN * 4;
    int* count     = (int*)p; p += (size_t)NN * 4;
    int* row_start = (int*)p; p += (size_t)(NN + 1) * 4;
    int* sp_start  = (int*)p; p += 16 * 4;

    k_pre<<<SEG, 1024, 0, stream>>>(W_embed, species, receivers,
                                    eslot, cnt16, (float4*)h0);
    k_colscan<<<NN / 128, 128, 0, stream>>>(cnt16, seg_base, count);
    k_scan<<<1, 1024, 0, stream>>>(count, row_start, species, nslot, sp_start);
    k_geom<<<NE / 256, 256, 0, stream>>>(positions, shifts, senders, receivers,
                                         row_start, seg_base, eslot, species,
                                         sp_start, nslot, ord, edgerec, ssend);

    // ---- iteration 0 ----
    k_aggmix<<<NN / 16, 512, 0, stream>>>(h0, edgerec, ssend, row_start,
        W_rad + 0, W_mix + 0, W_prod + 0, Bm0);
    k_sc<0><<<NN / SC_NPB, 256, 0, stream>>>(h0, Bm0, h1, ord, species,
        W_sc + 0, W_ro0, W_m1, b_m1, W_m2, out);

    // ---- iteration 1 ----
    k_aggmix<<<NN / 16, 512, 0, stream>>>(h1, edgerec, ssend, row_start,
        W_rad + 1536, W_mix + 12288, W_prod + 576, Bm0);
    k_sc<1><<<NN / SC_NPB, 256, 0, stream>>>(h1, Bm0, h0 /*unused*/, ord, species,
        W_sc + (size_t)NSPEC * 3 * 4096, W_ro0, W_m1, b_m1, W_m2, out);
}

// Round 21
// 264.670 us; speedup vs baseline: 1.6373x; 1.6373x over previous
//
#include <hip/hip_runtime.h>

#define NN 16384      // nodes
#define NE 262144     // edges
#define NSPEC 10
#define KC 64
#define MLPH 16
#define SEG 128       // edge segments
#define EPSG 2048     // edges per segment = NE/SEG
#define SC_NPB 16     // k_sc nodes per block (4 waves x 4)

typedef float v2f __attribute__((ext_vector_type(2)));

__device__ __forceinline__ float wave_reduce(float v) {
#pragma unroll
    for (int off = 32; off > 0; off >>= 1) v += __shfl_down(v, off, 64);
    return v;
}

__device__ __forceinline__ float f4c(const float4& v, int j) {
    const float* p = &v.x;   // j compile-time after unroll
    return p[j];
}

// 128 blocks x 1024 threads. Per-block PRIVATE full histogram in LDS (64 KB):
// eslot[e] = rank of edge within (segment, receiver) -- LDS fetch-add.
__global__ void __launch_bounds__(1024) k_pre(
    const float* __restrict__ W_embed,
    const int* __restrict__ species,
    const int* __restrict__ receivers,
    int* __restrict__ eslot,
    unsigned short* __restrict__ cnt16,    // [SEG][NN]
    float4* __restrict__ h04) {
    __shared__ int cntL[NN];
    int t = threadIdx.x;
#pragma unroll
    for (int i = 0; i < 16; ++i) cntL[t + 1024 * i] = 0;
    __syncthreads();
    int ebase = blockIdx.x * EPSG;
#pragma unroll
    for (int j = 0; j < EPSG / 1024; ++j) {
        int e = ebase + j * 1024 + t;
        int r = receivers[e];
        eslot[e] = atomicAdd(&cntL[r], 1);   // LDS atomic (ds_add_rtn)
    }
    int gt = blockIdx.x * 1024 + t;
#pragma unroll
    for (int q = 0; q < 2; ++q) {
        int idx = gt * 2 + q;
        int n = idx >> 4, w = idx & 15;
        h04[idx] = reinterpret_cast<const float4*>(W_embed + species[n] * KC)[w];
    }
    __syncthreads();
    unsigned short* o = cnt16 + (size_t)blockIdx.x * NN;
#pragma unroll
    for (int i = 0; i < 16; ++i)
        o[t + 1024 * i] = (unsigned short)cntL[t + 1024 * i];
}

// per-receiver column scan across segments (coalesced: thread = receiver)
__global__ void __launch_bounds__(128) k_colscan(
    const unsigned short* __restrict__ cnt16,
    int* __restrict__ seg_base,            // [SEG][NN]
    int* __restrict__ count) {
    int r = blockIdx.x * 128 + threadIdx.x;
    int run = 0;
#pragma unroll 8
    for (int g = 0; g < SEG; ++g) {
        int c = cnt16[(size_t)g * NN + r];
        seg_base[(size_t)g * NN + r] = run;
        run += c;
    }
    count[r] = run;
}

// single block: row_start scan + deterministic ballot-based species ranking
__global__ void __launch_bounds__(1024) k_scan(
    const int* __restrict__ count, int* __restrict__ row_start,
    const int* __restrict__ species, int* __restrict__ nslot,
    int* __restrict__ sp_start) {
    __shared__ int lds[1024];
    __shared__ int itercnt[256 * NSPEC];
    __shared__ int spt[NSPEC];
    int t = threadIdx.x;
    int lane = t & 63;
    int w = t >> 6;
#pragma unroll
    for (int j = 0; j < 16; ++j) {
        int n = w * 1024 + j * 64 + lane;
        int sp = species[n];
#pragma unroll
        for (int s = 0; s < NSPEC; ++s) {
            unsigned long long mask = __ballot(sp == s);
            if (lane == 0) itercnt[(w * 16 + j) * NSPEC + s] = (int)__popcll(mask);
        }
    }
    int base = t * 16;
    int local[16];
    int ssum = 0;
#pragma unroll
    for (int b = 0; b < 16; ++b) { local[b] = count[base + b]; ssum += local[b]; }
    lds[t] = ssum;
    __syncthreads();
    for (int off = 1; off < 1024; off <<= 1) {
        int v = (t >= off) ? lds[t - off] : 0;
        __syncthreads();
        lds[t] += v;
        __syncthreads();
    }
    int run = lds[t] - ssum;
#pragma unroll
    for (int b = 0; b < 16; ++b) { row_start[base + b] = run; run += local[b]; }
    if (t == 1023) row_start[NN] = run;
    __syncthreads();
    // per-species exclusive scan over 256 iter-entries: one wave per species
    if (w < NSPEC) {
        int s = w;
        int v0 = itercnt[(lane * 4 + 0) * NSPEC + s];
        int v1 = itercnt[(lane * 4 + 1) * NSPEC + s];
        int v2 = itercnt[(lane * 4 + 2) * NSPEC + s];
        int v3 = itercnt[(lane * 4 + 3) * NSPEC + s];
        int ls = v0 + v1 + v2 + v3;
        int inc = ls;
#pragma unroll
        for (int off = 1; off < 64; off <<= 1) {
            int v = __shfl_up(inc, off, 64);
            if (lane >= off) inc += v;
        }
        int exc = inc - ls;
        itercnt[(lane * 4 + 0) * NSPEC + s] = exc;
        itercnt[(lane * 4 + 1) * NSPEC + s] = exc + v0;
        itercnt[(lane * 4 + 2) * NSPEC + s] = exc + v0 + v1;
        itercnt[(lane * 4 + 3) * NSPEC + s] = exc + v0 + v1 + v2;
        if (lane == 63) spt[s] = inc;
    }
    __syncthreads();
    if (t == 0) {
        int r2 = 0;
        for (int s = 0; s < NSPEC; ++s) { sp_start[s] = r2; r2 += spt[s]; }
        sp_start[NSPEC] = r2;
    }
    __syncthreads();
#pragma unroll
    for (int j = 0; j < 16; ++j) {
        int n = w * 1024 + j * 64 + lane;
        int sp = species[n];
        int rank = 0;
#pragma unroll
        for (int s = 0; s < NSPEC; ++s) {
            unsigned long long mask = __ballot(sp == s);
            if (sp == s)
                rank = (int)__popcll(mask & ((1ull << lane) - 1ull));
        }
        nslot[n] = itercnt[(w * 16 + j) * NSPEC + sp] + rank;
    }
}

// geometry: 64B record [Y1..Y8, rad0..7] + separate sender array.
// sin via hardware v_sin_f32 (revolutions).  Also scatters ord.
__global__ void k_geom(const float* __restrict__ pos,
                       const float* __restrict__ shifts,
                       const int* __restrict__ senders,
                       const int* __restrict__ receivers,
                       const int* __restrict__ row_start,
                       const int* __restrict__ seg_base,
                       const int* __restrict__ eslot,
                       const int* __restrict__ species,
                       const int* __restrict__ sp_start,
                       const int* __restrict__ nslot,
                       int* __restrict__ ord,
                       float* __restrict__ edgerec,
                       int* __restrict__ ssend) {
    int e = blockIdx.x * 256 + threadIdx.x;
    if (e < NN) {
        int sp = species[e];
        ord[sp_start[sp] + nslot[e]] = e;
    }
    int s = senders[e], r = receivers[e];
    float dx = pos[r * 3 + 0] - pos[s * 3 + 0] + shifts[e * 3 + 0];
    float dy = pos[r * 3 + 1] - pos[s * 3 + 1] + shifts[e * 3 + 1];
    float dz = pos[r * 3 + 2] - pos[s * 3 + 2] + shifts[e * 3 + 2];
    float rn = sqrtf(dx * dx + dy * dy + dz * dz);
    float den = (rn > 1e-9f) ? rn : 1.0f;
    float x = dx / den, y = dy / den, z = dz / den;
    const float s3  = 1.7320508075688772f;
    const float s15 = 3.8729833462074170f;
    const float s5h = 1.1180339887498949f;
    const float s15h = 1.9364916731037085f;
    float rec[16];
    rec[0] = s3 * x;
    rec[1] = s3 * y;
    rec[2] = s3 * z;
    rec[3] = s15 * x * y;
    rec[4] = s15 * y * z;
    rec[5] = s5h * (3.0f * z * z - 1.0f);
    rec[6] = s15 * x * z;
    rec[7] = s15h * (x * x - y * y);
    float u = rn * 0.2f;
    float env = 0.0f;
    if (u < 1.0f) {
        float u2 = u * u;
        float u5 = u2 * u2 * u;
        env = 1.0f - 21.0f * u5 + 35.0f * u5 * u - 15.0f * u5 * u2;
    }
    float pre = 0.63245553203367587f * env / den;
    float half_u = 0.5f * u;
#pragma unroll
    for (int nb = 1; nb <= 8; ++nb) {
        float tr = (float)nb * half_u;       // revolutions
        tr -= floorf(tr);
        rec[7 + nb] = pre * __builtin_amdgcn_sinf(tr);
    }
    int p = row_start[r] + seg_base[(size_t)(e >> 11) * NN + r] + eslot[e];
    float4* o = (float4*)(edgerec + (size_t)p * 16);
#pragma unroll
    for (int i = 0; i < 4; ++i)
        o[i] = make_float4(rec[4 * i], rec[4 * i + 1], rec[4 * i + 2], rec[4 * i + 3]);
    ssend[p] = s;
}

// packed-fp32 per-edge accumulate; rec = [Y1..Y8, rad0..7], Y0==1 implicit.
__device__ __forceinline__ void agg_edge_pk(
    const float* __restrict__ rc, float hv,
    const float (&Wr0)[8], const v2f (&Wr12)[8],
    float& acc0, v2f (&accp)[4]) {
    float R0 = 0.f;
    v2f R12 = (v2f){0.f, 0.f};
#pragma unroll
    for (int b = 0; b < 8; ++b) {
        float rb = rc[8 + b];
        R0 = fmaf(rb, Wr0[b], R0);
        R12 = __builtin_elementwise_fma((v2f){rb, rb}, Wr12[b], R12);
    }
    acc0 = fmaf(hv, R0, acc0);
    float t1 = hv * R12.x, t2 = hv * R12.y;
    accp[0] = __builtin_elementwise_fma((v2f){t1, t1}, (v2f){rc[0], rc[1]}, accp[0]);
    accp[1] = __builtin_elementwise_fma((v2f){t1, t2}, (v2f){rc[2], rc[3]}, accp[1]);
    accp[2] = __builtin_elementwise_fma((v2f){t2, t2}, (v2f){rc[4], rc[5]}, accp[2]);
    accp[3] = __builtin_elementwise_fma((v2f){t2, t2}, (v2f){rc[6], rc[7]}, accp[3]);
}

// fused aggregate + mix + prod (R17 structure -- best measured).
// LDS = 16 KB (W_mix l=2) + 18 KB xtile = 34 KB -> 4 blocks/CU (32 waves).
__global__ void __launch_bounds__(512, 8) k_aggmix(
    const float* __restrict__ h,
    const float* __restrict__ edgerec,
    const int* __restrict__ ssend,
    const int* __restrict__ row_start,
    const float* __restrict__ Wr_i,    // [3][8][64]
    const float* __restrict__ Wm_i,    // [3][64][64]
    const float* __restrict__ Wp_i,    // [3][3][64]
    float* __restrict__ Bm0) {
    __shared__ float Wlds[4096];       // 16 KB: W_mix l=2
    __shared__ float xtile[8][9 * 64]; // 18 KB
    {
        float4* Wl4 = (float4*)Wlds;
        const float4* W4 = (const float4*)(Wm_i + 2 * 4096);   // l=2 start
#pragma unroll
        for (int i = 0; i < 2; ++i)
            Wl4[threadIdx.x + 512 * i] = W4[threadIdx.x + 512 * i];
    }
    __syncthreads();
    int lane = threadIdx.x & 63;
    int wid = __builtin_amdgcn_readfirstlane(threadIdx.x >> 6);
    float* xt = xtile[wid];
    float Wr0[8];
    v2f  Wr12[8];
#pragma unroll
    for (int b = 0; b < 8; ++b) {
        Wr0[b]    = Wr_i[b * 64 + lane] * (1.0f / 16.0f);
        Wr12[b].x = Wr_i[(8 + b) * 64 + lane] * (1.0f / 16.0f);
        Wr12[b].y = Wr_i[(16 + b) * 64 + lane] * (1.0f / 16.0f);
    }
    float w10 = Wp_i[0 * 64 + lane];
    float w20 = Wp_i[3 * 64 + lane];
    float w30 = Wp_i[6 * 64 + lane];
    const float* W0g = Wm_i;           // l=0 from global (L1)
    const float* W1g = Wm_i + 4096;    // l=1 from global (L1)

    int nA = (blockIdx.x * 8 + wid) * 2;
    int nB = nA + 1;
    int eA0 = row_start[nA], eA1 = row_start[nA + 1], eB1 = row_start[nB + 1];
    int eB0 = eA1;
    int cA = eA1 - eA0, cB = eB1 - eB0;
    int mc = min(cA, cB);

    float accA0 = 0.f, accB0 = 0.f;
    v2f accAp[4], accBp[4];
#pragma unroll
    for (int q = 0; q < 4; ++q) { accAp[q] = (v2f){0.f, 0.f}; accBp[q] = (v2f){0.f, 0.f}; }

#pragma unroll 2
    for (int i = 0; i < mc; ++i) {
        int ea = eA0 + i, eb = eB0 + i;
        int sa = ssend[ea], sb = ssend[eb];
        float ha = h[(size_t)sa * 64 + lane];
        float hb = h[(size_t)sb * 64 + lane];
        const float* ra = edgerec + (size_t)ea * 16;
        const float* rb = edgerec + (size_t)eb * 16;
        agg_edge_pk(ra, ha, Wr0, Wr12, accA0, accAp);
        agg_edge_pk(rb, hb, Wr0, Wr12, accB0, accBp);
    }
#pragma unroll 2
    for (int i = mc; i < cA; ++i) {
        int ea = eA0 + i;
        int sa = ssend[ea];
        float ha = h[(size_t)sa * 64 + lane];
        agg_edge_pk(edgerec + (size_t)ea * 16, ha, Wr0, Wr12, accA0, accAp);
    }
#pragma unroll 2
    for (int i = mc; i < cB; ++i) {
        int eb = eB0 + i;
        int sb = ssend[eb];
        float hb = h[(size_t)sb * 64 + lane];
        agg_edge_pk(edgerec + (size_t)eb * 16, hb, Wr0, Wr12, accB0, accBp);
    }

#pragma unroll
    for (int nn = 0; nn < 2; ++nn) {
        float a0 = nn ? accB0 : accA0;
        v2f* ap = nn ? accBp : accAp;
        int n = nn ? nB : nA;
        xt[0 * 64 + lane] = a0;
        xt[1 * 64 + lane] = ap[0].x;  xt[2 * 64 + lane] = ap[0].y;
        xt[3 * 64 + lane] = ap[1].x;  xt[4 * 64 + lane] = ap[1].y;
        xt[5 * 64 + lane] = ap[2].x;  xt[6 * 64 + lane] = ap[2].y;
        xt[7 * 64 + lane] = ap[3].x;  xt[8 * 64 + lane] = ap[3].y;
        v2f mixp[9];
#pragma unroll
        for (int m = 0; m < 9; ++m) mixp[m] = (v2f){0.f, 0.f};
#pragma unroll 2
        for (int c4 = 0; c4 < 16; ++c4) {
            float4 xb[9];
#pragma unroll
            for (int m = 0; m < 9; ++m)
                xb[m] = *(const float4*)&xt[m * 64 + c4 * 4];   // uniform b128
#pragma unroll
            for (int j2 = 0; j2 < 2; ++j2) {
                int k0 = c4 * 4 + j2 * 2;
                v2f wv0 = (v2f){W0g[k0 * 64 + lane], W0g[(k0 + 1) * 64 + lane]};
                v2f wv1 = (v2f){W1g[k0 * 64 + lane], W1g[(k0 + 1) * 64 + lane]};
                v2f wv2 = (v2f){Wlds[k0 * 64 + lane], Wlds[(k0 + 1) * 64 + lane]};
#pragma unroll
                for (int m = 0; m < 9; ++m) {
                    v2f xp = (v2f){f4c(xb[m], j2 * 2), f4c(xb[m], j2 * 2 + 1)};
                    v2f wv = (m == 0) ? wv0 : ((m < 4) ? wv1 : wv2);
                    mixp[m] = __builtin_elementwise_fma(xp, wv, mixp[m]);
                }
            }
        }
        float mix[9];
#pragma unroll
        for (int m = 0; m < 9; ++m) mix[m] = mixp[m].x + mixp[m].y;
        float A0 = mix[0];
        float inv = 0.f;
#pragma unroll
        for (int m = 0; m < 9; ++m) inv += mix[m] * mix[m];
        Bm0[(size_t)n * 64 + lane] = mix[0] * (w10 + w20 * A0 + w30 * inv);
    }
}

// l=0 self-connection + energy epilogue.  Balanced grid: block b owns sorted
// slots [b*16, b*16+16) of ord -- every block works.  W of first node's
// species staged in LDS; rare species-boundary nodes recomputed via global W.
template <int ITER>
__global__ void __launch_bounds__(256) k_sc(
    const float* __restrict__ h_in,
    const float* __restrict__ Bm0,
    float* __restrict__ h_out,
    const int* __restrict__ ord,
    const int* __restrict__ species,
    const float* __restrict__ Wsc_i,     // + sp*3*4096 selects [sp][l=0]
    const float* __restrict__ W_ro0,
    const float* __restrict__ W_m1,
    const float* __restrict__ b_m1,
    const float* __restrict__ W_m2,
    float* __restrict__ out) {
    __shared__ float Wlds[4096];
    __shared__ float xtile[4][4 * 64];
    int idx0 = blockIdx.x * SC_NPB;
    int s0 = species[ord[idx0]];          // uniform -> scalar loads
    {
        const float4* W4 = (const float4*)(Wsc_i + (size_t)s0 * 3 * 4096);
        float4* Wl4 = (float4*)Wlds;
#pragma unroll
        for (int i = 0; i < 4; ++i)
            Wl4[threadIdx.x + 256 * i] = W4[threadIdx.x + 256 * i];
    }
    __syncthreads();
    int lane = threadIdx.x & 63;
    int wid = threadIdx.x >> 6;
    float* xt = xtile[wid];
    int q0 = idx0 + wid * 4;
    int nd[4];
#pragma unroll
    for (int t = 0; t < 4; ++t) nd[t] = ord[q0 + t];
    float xv[4];
#pragma unroll
    for (int t = 0; t < 4; ++t) xv[t] = h_in[(size_t)nd[t] * 64 + lane];
#pragma unroll
    for (int t = 0; t < 4; ++t) xt[t * 64 + lane] = xv[t];
    float acc[4] = {0.f, 0.f, 0.f, 0.f};
#pragma unroll 4
    for (int c4 = 0; c4 < 16; ++c4) {
        float wv[4];
#pragma unroll
        for (int j = 0; j < 4; ++j) wv[j] = Wlds[(c4 * 4 + j) * 64 + lane];
#pragma unroll
        for (int t = 0; t < 4; ++t) {
            float4 xb = *(const float4*)&xt[t * 64 + c4 * 4];
#pragma unroll
            for (int j = 0; j < 4; ++j) acc[t] += f4c(xb, j) * wv[j];
        }
    }
    // rare species-boundary fixup (wave-uniform condition)
#pragma unroll
    for (int t = 0; t < 4; ++t) {
        int spt = species[nd[t]];
        if (spt != s0) {
            const float* Wg = Wsc_i + (size_t)spt * 3 * 4096;
            float a = 0.f;
            for (int k = 0; k < 64; ++k)
                a += xt[t * 64 + k] * Wg[k * 64 + lane];
            acc[t] = a;
        }
    }
    float wro = W_ro0[lane];
#pragma unroll
    for (int t = 0; t < 4; ++t) {
        int node = nd[t];
        float outv = acc[t] + Bm0[(size_t)node * 64 + lane];
        if (ITER == 0) {
            h_out[(size_t)node * 64 + lane] = outv;
            float e = wave_reduce(outv * wro);
            if (lane == 0) out[2 * node + 0] = e;
        } else {
            int hh = lane & 15;
            float tacc = b_m1[hh];
#pragma unroll
            for (int k = 0; k < 64; ++k)
                tacc += __shfl(outv, k, 64) * W_m1[k * MLPH + hh];
            float sig = 1.0f / (1.0f + expf(-tacc));
            float contrib = (lane < MLPH) ? tacc * sig * W_m2[lane] : 0.f;
            float e = wave_reduce(contrib);
            if (lane == 0) out[2 * node + 1] = e;
        }
    }
}

extern "C" void kernel_launch(void* const* d_in, const int* in_sizes, int n_in,
                              void* d_out, int out_size, void* d_ws, size_t ws_size,
                              hipStream_t stream) {
    const float* positions = (const float*)d_in[0];
    const float* shifts    = (const float*)d_in[1];
    const int*   species   = (const int*)d_in[2];
    const int*   senders   = (const int*)d_in[3];
    const int*   receivers = (const int*)d_in[4];
    const float* W_embed   = (const float*)d_in[5];
    const float* W_rad     = (const float*)d_in[6];
    const float* W_mix     = (const float*)d_in[7];
    const float* W_prod    = (const float*)d_in[8];
    const float* W_sc      = (const float*)d_in[9];
    const float* W_ro0     = (const float*)d_in[10];
    const float* W_m1      = (const float*)d_in[11];
    const float* b_m1      = (const float*)d_in[12];
    const float* W_m2      = (const float*)d_in[13];
    float* out = (float*)d_out;

    char* p = (char*)d_ws;
    float* edgerec = (float*)p; p += (size_t)NE * 16 * 4;    // 16.78 MB
    int* seg_base  = (int*)p;   p += (size_t)SEG * NN * 4;   //  8.39 MB
    float* Bm0     = (float*)p; p += (size_t)NN * KC * 4;    //  4.19 MB
    float* h0      = (float*)p; p += (size_t)NN * KC * 4;    //  4.19 MB
    float* h1      = (float*)p; p += (size_t)NN * KC * 4;    //  4.19 MB
    unsigned short* cnt16 = (unsigned short*)p; p += (size_t)SEG * NN * 2; // 4.19 MB
    int* eslot     = (int*)p; p += (size_t)NE * 4;           //  1.05 MB
    int* ssend     = (int*)p; p += (size_t)NE * 4;           //  1.05 MB
    int* nslot     = (int*)p; p += (size_t)NN * 4;
    int* ord       = (int*)p; p += (size_t)NN * 4;
    int* count     = (int*)p; p += (size_t)NN * 4;
    int* row_start = (int*)p; p += (size_t)(NN + 1) * 4;
    int* sp_start  = (int*)p; p += 16 * 4;

    k_pre<<<SEG, 1024, 0, stream>>>(W_embed, species, receivers,
                                    eslot, cnt16, (float4*)h0);
    k_colscan<<<NN / 128, 128, 0, stream>>>(cnt16, seg_base, count);
    k_scan<<<1, 1024, 0, stream>>>(count, row_start, species, nslot, sp_start);
    k_geom<<<NE / 256, 256, 0, stream>>>(positions, shifts, senders, receivers,
                                         row_start, seg_base, eslot, species,
                                         sp_start, nslot, ord, edgerec, ssend);

    // ---- iteration 0 ----
    k_aggmix<<<NN / 16, 512, 0, stream>>>(h0, edgerec, ssend, row_start,
        W_rad + 0, W_mix + 0, W_prod + 0, Bm0);
    k_sc<0><<<NN / SC_NPB, 256, 0, stream>>>(h0, Bm0, h1, ord, species,
        W_sc + 0, W_ro0, W_m1, b_m1, W_m2, out);

    // ---- iteration 1 ----
    k_aggmix<<<NN / 16, 512, 0, stream>>>(h1, edgerec, ssend, row_start,
        W_rad + 1536, W_mix + 12288, W_prod + 576, Bm0);
    k_sc<1><<<NN / SC_NPB, 256, 0, stream>>>(h1, Bm0, h0 /*unused*/, ord, species,
        W_sc + (size_t)NSPEC * 3 * 4096, W_ro0, W_m1, b_m1, W_m2, out);
}

// Round 22
// 250.721 us; speedup vs baseline: 1.7284x; 1.0556x over previous
//
#include <hip/hip_runtime.h>

#define NN 16384      // nodes
#define NE 262144     // edges
#define NSPEC 10
#define KC 64
#define MLPH 16
#define SEG 128       // edge segments
#define EPSG 2048     // edges per segment = NE/SEG
#define NCHUNK 256    // node chunks of 64 (NN/64)
#define SC_NPB 16     // k_sc nodes per block (4 waves x 4)

typedef float v2f __attribute__((ext_vector_type(2)));

__device__ __forceinline__ float wave_reduce(float v) {
#pragma unroll
    for (int off = 32; off > 0; off >>= 1) v += __shfl_down(v, off, 64);
    return v;
}

__device__ __forceinline__ float f4c(const float4& v, int j) {
    const float* p = &v.x;   // j compile-time after unroll
    return p[j];
}

// 128 blocks x 1024 threads. Per-block PRIVATE full histogram in LDS (64 KB):
// eslot[e] = rank of edge within (segment, receiver) -- LDS fetch-add.
// Also: per-wave deterministic species ranking (nslot, chunkcnt) + h0 init.
__global__ void __launch_bounds__(1024) k_pre(
    const float* __restrict__ W_embed,
    const int* __restrict__ species,
    const int* __restrict__ receivers,
    int* __restrict__ eslot,
    unsigned short* __restrict__ cnt16,    // [SEG][NN]
    int* __restrict__ nslot,
    int* __restrict__ chunkcnt,            // [NCHUNK][NSPEC]
    float4* __restrict__ h04) {
    __shared__ int cntL[NN];
    int t = threadIdx.x;
    int lane = t & 63;
#pragma unroll
    for (int i = 0; i < 16; ++i) cntL[t + 1024 * i] = 0;
    __syncthreads();
    int ebase = blockIdx.x * EPSG;
#pragma unroll
    for (int j = 0; j < EPSG / 1024; ++j) {
        int e = ebase + j * 1024 + t;
        int r = receivers[e];
        eslot[e] = atomicAdd(&cntL[r], 1);   // LDS atomic (ds_add_rtn)
    }
    int tid = blockIdx.x * 1024 + t;
    if (tid < NN) {    // blocks 0..15 entirely -> wave-uniform
        int sp = species[tid];
        int rank = 0, mycnt = 0;
#pragma unroll
        for (int s = 0; s < NSPEC; ++s) {
            unsigned long long mask = __ballot(sp == s);
            if (sp == s) rank = (int)__popcll(mask & ((1ull << lane) - 1ull));
            if (lane == s) mycnt = (int)__popcll(mask);
        }
        nslot[tid] = rank;
        if (lane < NSPEC) chunkcnt[(tid >> 6) * NSPEC + lane] = mycnt;
    }
    int gt = tid;
#pragma unroll
    for (int q = 0; q < 2; ++q) {
        int idx = gt * 2 + q;
        int n = idx >> 4, w = idx & 15;
        h04[idx] = reinterpret_cast<const float4*>(W_embed + species[n] * KC)[w];
    }
    __syncthreads();
    unsigned short* o = cnt16 + (size_t)blockIdx.x * NN;
#pragma unroll
    for (int i = 0; i < 16; ++i)
        o[t + 1024 * i] = (unsigned short)cntL[t + 1024 * i];
}

// per-receiver column scan across segments (coalesced: thread = receiver)
__global__ void __launch_bounds__(128) k_colscan(
    const unsigned short* __restrict__ cnt16,
    int* __restrict__ seg_base,            // [SEG][NN]
    int* __restrict__ count) {
    int r = blockIdx.x * 128 + threadIdx.x;
    int run = 0;
#pragma unroll 8
    for (int g = 0; g < SEG; ++g) {
        int c = cnt16[(size_t)g * NN + r];
        seg_base[(size_t)g * NN + r] = run;
        run += c;
    }
    count[r] = run;
}

// single block, lightweight: row_start scan (shfl wave-scan, 3 barriers) +
// per-species chunk-base scan (256 entries, one wave/species) + sp_start.
__global__ void __launch_bounds__(1024) k_scan(
    const int* __restrict__ count, int* __restrict__ row_start,
    const int* __restrict__ chunkcnt,   // [NCHUNK][NSPEC]
    int* __restrict__ cbase,            // [NCHUNK][NSPEC]
    int* __restrict__ sp_start) {
    __shared__ int wsum[16];
    __shared__ int spt[NSPEC];
    int t = threadIdx.x;
    int lane = t & 63;
    int w = t >> 6;
    int base = t * 16;
    int local[16];
    int ssum = 0;
#pragma unroll
    for (int b = 0; b < 16; ++b) { local[b] = count[base + b]; ssum += local[b]; }
    int inc = ssum;
#pragma unroll
    for (int off = 1; off < 64; off <<= 1) {
        int v = __shfl_up(inc, off, 64);
        if (lane >= off) inc += v;
    }
    if (lane == 63) wsum[w] = inc;
    __syncthreads();
    if (w == 0) {
        int v = (lane < 16) ? wsum[lane] : 0;
        int inc2 = v;
#pragma unroll
        for (int off = 1; off < 16; off <<= 1) {
            int u = __shfl_up(inc2, off, 64);
            if (lane >= off) inc2 += u;
        }
        if (lane < 16) wsum[lane] = inc2 - v;   // exclusive
    }
    __syncthreads();
    int run = wsum[w] + (inc - ssum);
#pragma unroll
    for (int b = 0; b < 16; ++b) { row_start[base + b] = run; run += local[b]; }
    if (t == 1023) row_start[NN] = run;
    // species chunk scan: one wave per species over NCHUNK entries
    if (w < NSPEC) {
        int s = w;
        int v0 = chunkcnt[(lane * 4 + 0) * NSPEC + s];
        int v1 = chunkcnt[(lane * 4 + 1) * NSPEC + s];
        int v2 = chunkcnt[(lane * 4 + 2) * NSPEC + s];
        int v3 = chunkcnt[(lane * 4 + 3) * NSPEC + s];
        int ls = v0 + v1 + v2 + v3;
        int inc3 = ls;
#pragma unroll
        for (int off = 1; off < 64; off <<= 1) {
            int v = __shfl_up(inc3, off, 64);
            if (lane >= off) inc3 += v;
        }
        int exc = inc3 - ls;
        cbase[(lane * 4 + 0) * NSPEC + s] = exc;
        cbase[(lane * 4 + 1) * NSPEC + s] = exc + v0;
        cbase[(lane * 4 + 2) * NSPEC + s] = exc + v0 + v1;
        cbase[(lane * 4 + 3) * NSPEC + s] = exc + v0 + v1 + v2;
        if (lane == 63) spt[s] = inc3;
    }
    __syncthreads();
    if (t == 0) {
        int r2 = 0;
        for (int s = 0; s < NSPEC; ++s) { sp_start[s] = r2; r2 += spt[s]; }
        sp_start[NSPEC] = r2;
    }
}

// geometry: 64B record [Y1..Y8, rad0..7] + separate sender array.
// sin via hardware v_sin_f32 (revolutions).  Also scatters ord
// (p = sp_start + chunk base + in-wave rank).
__global__ void k_geom(const float* __restrict__ pos,
                       const float* __restrict__ shifts,
                       const int* __restrict__ senders,
                       const int* __restrict__ receivers,
                       const int* __restrict__ row_start,
                       const int* __restrict__ seg_base,
                       const int* __restrict__ eslot,
                       const int* __restrict__ species,
                       const int* __restrict__ sp_start,
                       const int* __restrict__ cbase,
                       const int* __restrict__ nslot,
                       int* __restrict__ ord,
                       float* __restrict__ edgerec,
                       int* __restrict__ ssend) {
    int e = blockIdx.x * 256 + threadIdx.x;
    if (e < NN) {
        int sp = species[e];
        ord[sp_start[sp] + cbase[(e >> 6) * NSPEC + sp] + nslot[e]] = e;
    }
    int s = senders[e], r = receivers[e];
    float dx = pos[r * 3 + 0] - pos[s * 3 + 0] + shifts[e * 3 + 0];
    float dy = pos[r * 3 + 1] - pos[s * 3 + 1] + shifts[e * 3 + 1];
    float dz = pos[r * 3 + 2] - pos[s * 3 + 2] + shifts[e * 3 + 2];
    float rn = sqrtf(dx * dx + dy * dy + dz * dz);
    float den = (rn > 1e-9f) ? rn : 1.0f;
    float x = dx / den, y = dy / den, z = dz / den;
    const float s3  = 1.7320508075688772f;
    const float s15 = 3.8729833462074170f;
    const float s5h = 1.1180339887498949f;
    const float s15h = 1.9364916731037085f;
    float rec[16];
    rec[0] = s3 * x;
    rec[1] = s3 * y;
    rec[2] = s3 * z;
    rec[3] = s15 * x * y;
    rec[4] = s15 * y * z;
    rec[5] = s5h * (3.0f * z * z - 1.0f);
    rec[6] = s15 * x * z;
    rec[7] = s15h * (x * x - y * y);
    float u = rn * 0.2f;
    float env = 0.0f;
    if (u < 1.0f) {
        float u2 = u * u;
        float u5 = u2 * u2 * u;
        env = 1.0f - 21.0f * u5 + 35.0f * u5 * u - 15.0f * u5 * u2;
    }
    float pre = 0.63245553203367587f * env / den;
    float half_u = 0.5f * u;
#pragma unroll
    for (int nb = 1; nb <= 8; ++nb) {
        float tr = (float)nb * half_u;       // revolutions
        tr -= floorf(tr);
        rec[7 + nb] = pre * __builtin_amdgcn_sinf(tr);
    }
    int p = row_start[r] + seg_base[(size_t)(e >> 11) * NN + r] + eslot[e];
    float4* o = (float4*)(edgerec + (size_t)p * 16);
#pragma unroll
    for (int i = 0; i < 4; ++i)
        o[i] = make_float4(rec[4 * i], rec[4 * i + 1], rec[4 * i + 2], rec[4 * i + 3]);
    ssend[p] = s;
}

// packed-fp32 per-edge accumulate; rec = [Y1..Y8, rad0..7], Y0==1 implicit.
__device__ __forceinline__ void agg_edge_pk(
    const float* __restrict__ rc, float hv,
    const float (&Wr0)[8], const v2f (&Wr12)[8],
    float& acc0, v2f (&accp)[4]) {
    float R0 = 0.f;
    v2f R12 = (v2f){0.f, 0.f};
#pragma unroll
    for (int b = 0; b < 8; ++b) {
        float rb = rc[8 + b];
        R0 = fmaf(rb, Wr0[b], R0);
        R12 = __builtin_elementwise_fma((v2f){rb, rb}, Wr12[b], R12);
    }
    acc0 = fmaf(hv, R0, acc0);
    float t1 = hv * R12.x, t2 = hv * R12.y;
    accp[0] = __builtin_elementwise_fma((v2f){t1, t1}, (v2f){rc[0], rc[1]}, accp[0]);
    accp[1] = __builtin_elementwise_fma((v2f){t1, t2}, (v2f){rc[2], rc[3]}, accp[1]);
    accp[2] = __builtin_elementwise_fma((v2f){t2, t2}, (v2f){rc[4], rc[5]}, accp[2]);
    accp[3] = __builtin_elementwise_fma((v2f){t2, t2}, (v2f){rc[6], rc[7]}, accp[3]);
}

// fused aggregate + mix + prod (R17 structure -- best measured).
// LDS = 16 KB (W_mix l=2) + 18 KB xtile = 34 KB -> 4 blocks/CU (32 waves).
__global__ void __launch_bounds__(512, 8) k_aggmix(
    const float* __restrict__ h,
    const float* __restrict__ edgerec,
    const int* __restrict__ ssend,
    const int* __restrict__ row_start,
    const float* __restrict__ Wr_i,    // [3][8][64]
    const float* __restrict__ Wm_i,    // [3][64][64]
    const float* __restrict__ Wp_i,    // [3][3][64]
    float* __restrict__ Bm0) {
    __shared__ float Wlds[4096];       // 16 KB: W_mix l=2
    __shared__ float xtile[8][9 * 64]; // 18 KB
    {
        float4* Wl4 = (float4*)Wlds;
        const float4* W4 = (const float4*)(Wm_i + 2 * 4096);   // l=2 start
#pragma unroll
        for (int i = 0; i < 2; ++i)
            Wl4[threadIdx.x + 512 * i] = W4[threadIdx.x + 512 * i];
    }
    __syncthreads();
    int lane = threadIdx.x & 63;
    int wid = __builtin_amdgcn_readfirstlane(threadIdx.x >> 6);
    float* xt = xtile[wid];
    float Wr0[8];
    v2f  Wr12[8];
#pragma unroll
    for (int b = 0; b < 8; ++b) {
        Wr0[b]    = Wr_i[b * 64 + lane] * (1.0f / 16.0f);
        Wr12[b].x = Wr_i[(8 + b) * 64 + lane] * (1.0f / 16.0f);
        Wr12[b].y = Wr_i[(16 + b) * 64 + lane] * (1.0f / 16.0f);
    }
    float w10 = Wp_i[0 * 64 + lane];
    float w20 = Wp_i[3 * 64 + lane];
    float w30 = Wp_i[6 * 64 + lane];
    const float* W0g = Wm_i;           // l=0 from global (L1)
    const float* W1g = Wm_i + 4096;    // l=1 from global (L1)

    int nA = (blockIdx.x * 8 + wid) * 2;
    int nB = nA + 1;
    int eA0 = row_start[nA], eA1 = row_start[nA + 1], eB1 = row_start[nB + 1];
    int eB0 = eA1;
    int cA = eA1 - eA0, cB = eB1 - eB0;
    int mc = min(cA, cB);

    float accA0 = 0.f, accB0 = 0.f;
    v2f accAp[4], accBp[4];
#pragma unroll
    for (int q = 0; q < 4; ++q) { accAp[q] = (v2f){0.f, 0.f}; accBp[q] = (v2f){0.f, 0.f}; }

#pragma unroll 2
    for (int i = 0; i < mc; ++i) {
        int ea = eA0 + i, eb = eB0 + i;
        int sa = ssend[ea], sb = ssend[eb];
        float ha = h[(size_t)sa * 64 + lane];
        float hb = h[(size_t)sb * 64 + lane];
        const float* ra = edgerec + (size_t)ea * 16;
        const float* rb = edgerec + (size_t)eb * 16;
        agg_edge_pk(ra, ha, Wr0, Wr12, accA0, accAp);
        agg_edge_pk(rb, hb, Wr0, Wr12, accB0, accBp);
    }
#pragma unroll 2
    for (int i = mc; i < cA; ++i) {
        int ea = eA0 + i;
        int sa = ssend[ea];
        float ha = h[(size_t)sa * 64 + lane];
        agg_edge_pk(edgerec + (size_t)ea * 16, ha, Wr0, Wr12, accA0, accAp);
    }
#pragma unroll 2
    for (int i = mc; i < cB; ++i) {
        int eb = eB0 + i;
        int sb = ssend[eb];
        float hb = h[(size_t)sb * 64 + lane];
        agg_edge_pk(edgerec + (size_t)eb * 16, hb, Wr0, Wr12, accB0, accBp);
    }

#pragma unroll
    for (int nn = 0; nn < 2; ++nn) {
        float a0 = nn ? accB0 : accA0;
        v2f* ap = nn ? accBp : accAp;
        int n = nn ? nB : nA;
        xt[0 * 64 + lane] = a0;
        xt[1 * 64 + lane] = ap[0].x;  xt[2 * 64 + lane] = ap[0].y;
        xt[3 * 64 + lane] = ap[1].x;  xt[4 * 64 + lane] = ap[1].y;
        xt[5 * 64 + lane] = ap[2].x;  xt[6 * 64 + lane] = ap[2].y;
        xt[7 * 64 + lane] = ap[3].x;  xt[8 * 64 + lane] = ap[3].y;
        v2f mixp[9];
#pragma unroll
        for (int m = 0; m < 9; ++m) mixp[m] = (v2f){0.f, 0.f};
#pragma unroll 2
        for (int c4 = 0; c4 < 16; ++c4) {
            float4 xb[9];
#pragma unroll
            for (int m = 0; m < 9; ++m)
                xb[m] = *(const float4*)&xt[m * 64 + c4 * 4];   // uniform b128
#pragma unroll
            for (int j2 = 0; j2 < 2; ++j2) {
                int k0 = c4 * 4 + j2 * 2;
                v2f wv0 = (v2f){W0g[k0 * 64 + lane], W0g[(k0 + 1) * 64 + lane]};
                v2f wv1 = (v2f){W1g[k0 * 64 + lane], W1g[(k0 + 1) * 64 + lane]};
                v2f wv2 = (v2f){Wlds[k0 * 64 + lane], Wlds[(k0 + 1) * 64 + lane]};
#pragma unroll
                for (int m = 0; m < 9; ++m) {
                    v2f xp = (v2f){f4c(xb[m], j2 * 2), f4c(xb[m], j2 * 2 + 1)};
                    v2f wv = (m == 0) ? wv0 : ((m < 4) ? wv1 : wv2);
                    mixp[m] = __builtin_elementwise_fma(xp, wv, mixp[m]);
                }
            }
        }
        float mix[9];
#pragma unroll
        for (int m = 0; m < 9; ++m) mix[m] = mixp[m].x + mixp[m].y;
        float A0 = mix[0];
        float inv = 0.f;
#pragma unroll
        for (int m = 0; m < 9; ++m) inv += mix[m] * mix[m];
        Bm0[(size_t)n * 64 + lane] = mix[0] * (w10 + w20 * A0 + w30 * inv);
    }
}

// l=0 self-connection + energy epilogue.  Balanced grid: block b owns sorted
// slots [b*16, b*16+16) of ord -- every block works.  W of first node's
// species staged in LDS; rare species-boundary nodes recomputed via global W.
template <int ITER>
__global__ void __launch_bounds__(256) k_sc(
    const float* __restrict__ h_in,
    const float* __restrict__ Bm0,
    float* __restrict__ h_out,
    const int* __restrict__ ord,
    const int* __restrict__ species,
    const float* __restrict__ Wsc_i,     // + sp*3*4096 selects [sp][l=0]
    const float* __restrict__ W_ro0,
    const float* __restrict__ W_m1,
    const float* __restrict__ b_m1,
    const float* __restrict__ W_m2,
    float* __restrict__ out) {
    __shared__ float Wlds[4096];
    __shared__ float xtile[4][4 * 64];
    int idx0 = blockIdx.x * SC_NPB;
    int s0 = species[ord[idx0]];          // uniform -> scalar loads
    {
        const float4* W4 = (const float4*)(Wsc_i + (size_t)s0 * 3 * 4096);
        float4* Wl4 = (float4*)Wlds;
#pragma unroll
        for (int i = 0; i < 4; ++i)
            Wl4[threadIdx.x + 256 * i] = W4[threadIdx.x + 256 * i];
    }
    __syncthreads();
    int lane = threadIdx.x & 63;
    int wid = threadIdx.x >> 6;
    float* xt = xtile[wid];
    int q0 = idx0 + wid * 4;
    int nd[4];
#pragma unroll
    for (int t = 0; t < 4; ++t) nd[t] = ord[q0 + t];
    float xv[4];
#pragma unroll
    for (int t = 0; t < 4; ++t) xv[t] = h_in[(size_t)nd[t] * 64 + lane];
#pragma unroll
    for (int t = 0; t < 4; ++t) xt[t * 64 + lane] = xv[t];
    float acc[4] = {0.f, 0.f, 0.f, 0.f};
#pragma unroll 4
    for (int c4 = 0; c4 < 16; ++c4) {
        float wv[4];
#pragma unroll
        for (int j = 0; j < 4; ++j) wv[j] = Wlds[(c4 * 4 + j) * 64 + lane];
#pragma unroll
        for (int t = 0; t < 4; ++t) {
            float4 xb = *(const float4*)&xt[t * 64 + c4 * 4];
#pragma unroll
            for (int j = 0; j < 4; ++j) acc[t] += f4c(xb, j) * wv[j];
        }
    }
    // rare species-boundary fixup (wave-uniform condition)
#pragma unroll
    for (int t = 0; t < 4; ++t) {
        int spt = species[nd[t]];
        if (spt != s0) {
            const float* Wg = Wsc_i + (size_t)spt * 3 * 4096;
            float a = 0.f;
            for (int k = 0; k < 64; ++k)
                a += xt[t * 64 + k] * Wg[k * 64 + lane];
            acc[t] = a;
        }
    }
    float wro = W_ro0[lane];
#pragma unroll
    for (int t = 0; t < 4; ++t) {
        int node = nd[t];
        float outv = acc[t] + Bm0[(size_t)node * 64 + lane];
        if (ITER == 0) {
            h_out[(size_t)node * 64 + lane] = outv;
            float e = wave_reduce(outv * wro);
            if (lane == 0) out[2 * node + 0] = e;
        } else {
            int hh = lane & 15;
            float tacc = b_m1[hh];
#pragma unroll
            for (int k = 0; k < 64; ++k)
                tacc += __shfl(outv, k, 64) * W_m1[k * MLPH + hh];
            float sig = 1.0f / (1.0f + expf(-tacc));
            float contrib = (lane < MLPH) ? tacc * sig * W_m2[lane] : 0.f;
            float e = wave_reduce(contrib);
            if (lane == 0) out[2 * node + 1] = e;
        }
    }
}

extern "C" void kernel_launch(void* const* d_in, const int* in_sizes, int n_in,
                              void* d_out, int out_size, void* d_ws, size_t ws_size,
                              hipStream_t stream) {
    const float* positions = (const float*)d_in[0];
    const float* shifts    = (const float*)d_in[1];
    const int*   species   = (const int*)d_in[2];
    const int*   senders   = (const int*)d_in[3];
    const int*   receivers = (const int*)d_in[4];
    const float* W_embed   = (const float*)d_in[5];
    const float* W_rad     = (const float*)d_in[6];
    const float* W_mix     = (const float*)d_in[7];
    const float* W_prod    = (const float*)d_in[8];
    const float* W_sc      = (const float*)d_in[9];
    const float* W_ro0     = (const float*)d_in[10];
    const float* W_m1      = (const float*)d_in[11];
    const float* b_m1      = (const float*)d_in[12];
    const float* W_m2      = (const float*)d_in[13];
    float* out = (float*)d_out;

    char* p = (char*)d_ws;
    float* edgerec = (float*)p; p += (size_t)NE * 16 * 4;    // 16.78 MB
    int* seg_base  = (int*)p;   p += (size_t)SEG * NN * 4;   //  8.39 MB
    float* Bm0     = (float*)p; p += (size_t)NN * KC * 4;    //  4.19 MB
    float* h0      = (float*)p; p += (size_t)NN * KC * 4;    //  4.19 MB
    float* h1      = (float*)p; p += (size_t)NN * KC * 4;    //  4.19 MB
    unsigned short* cnt16 = (unsigned short*)p; p += (size_t)SEG * NN * 2; // 4.19 MB
    int* eslot     = (int*)p; p += (size_t)NE * 4;           //  1.05 MB
    int* ssend     = (int*)p; p += (size_t)NE * 4;           //  1.05 MB
    int* nslot     = (int*)p; p += (size_t)NN * 4;
    int* ord       = (int*)p; p += (size_t)NN * 4;
    int* count     = (int*)p; p += (size_t)NN * 4;
    int* row_start = (int*)p; p += (size_t)(NN + 1) * 4;
    int* chunkcnt  = (int*)p; p += (size_t)NCHUNK * NSPEC * 4;
    int* cbase     = (int*)p; p += (size_t)NCHUNK * NSPEC * 4;
    int* sp_start  = (int*)p; p += 16 * 4;

    k_pre<<<SEG, 1024, 0, stream>>>(W_embed, species, receivers,
                                    eslot, cnt16, nslot, chunkcnt, (float4*)h0);
    k_colscan<<<NN / 128, 128, 0, stream>>>(cnt16, seg_base, count);
    k_scan<<<1, 1024, 0, stream>>>(count, row_start, chunkcnt, cbase, sp_start);
    k_geom<<<NE / 256, 256, 0, stream>>>(positions, shifts, senders, receivers,
                                         row_start, seg_base, eslot, species,
                                         sp_start, cbase, nslot, ord,
                                         edgerec, ssend);

    // ---- iteration 0 ----
    k_aggmix<<<NN / 16, 512, 0, stream>>>(h0, edgerec, ssend, row_start,
        W_rad + 0, W_mix + 0, W_prod + 0, Bm0);
    k_sc<0><<<NN / SC_NPB, 256, 0, stream>>>(h0, Bm0, h1, ord, species,
        W_sc + 0, W_ro0, W_m1, b_m1, W_m2, out);

    // ---- iteration 1 ----
    k_aggmix<<<NN / 16, 512, 0, stream>>>(h1, edgerec, ssend, row_start,
        W_rad + 1536, W_mix + 12288, W_prod + 576, Bm0);
    k_sc<1><<<NN / SC_NPB, 256, 0, stream>>>(h1, Bm0, h0 /*unused*/, ord, species,
        W_sc + (size_t)NSPEC * 3 * 4096, W_ro0, W_m1, b_m1, W_m2, out);
}